// Round 1
// baseline (591.271 us; speedup 1.0000x reference)
//
#include <hip/hip_runtime.h>

// Problem constants
static constexpr int NROWS = 32768;
static constexpr int FIN   = 1024;
static constexpr int FOUT  = 512;

// ws layout:
//   double e[32768]      : unnormalized exp(scores)
//   double scal[8]       : scal[0] = Z (sum of e), scal[1] = c0 (h@W@a1 scalar)
//   float  v[1024]       : W @ a2
//   float  u[1024]       : sum_i e_i * adj[i][:]  (unnormalized attention @ adj)
static constexpr size_t WS_E_DOUBLES  = NROWS;
static constexpr size_t WS_USED_BYTES = NROWS * 8 + 64 + FIN * 4 + FIN * 4;

// ---------------------------------------------------------------------------
// K1: one wave per k (1024 waves).
//   v[k]  = sum_j W[k][j] * a2[j]          (a2 = a[512:1024])
//   c0   += h[k] * (sum_j W[k][j] * a1[j]) (a1 = a[0:512]), fp64 atomic
// ---------------------------------------------------------------------------
__global__ __launch_bounds__(256) void k1_prep(const float* __restrict__ W,
                                               const float* __restrict__ a,
                                               const float* __restrict__ h,
                                               float* __restrict__ v,
                                               double* __restrict__ scal) {
    const int wave = (blockIdx.x * blockDim.x + threadIdx.x) >> 6;  // 0..1023
    const int lane = threadIdx.x & 63;
    const int k = wave;

    const float4* Wrow = (const float4*)(W + (size_t)k * FOUT);
    float4 w0 = Wrow[lane];        // cols 4l .. 4l+3
    float4 w1 = Wrow[64 + lane];   // cols 256+4l ..

    const float4* a4 = (const float4*)a;
    float4 a1_0 = a4[lane];        // a[4l..]        (a1 seg0)
    float4 a1_1 = a4[64 + lane];   // a[256+4l..]    (a1 seg1)
    float4 a2_0 = a4[128 + lane];  // a[512+4l..]    (a2 seg0)
    float4 a2_1 = a4[192 + lane];  // a[768+4l..]    (a2 seg1)

    double d1 = (double)w0.x * a1_0.x + (double)w0.y * a1_0.y +
                (double)w0.z * a1_0.z + (double)w0.w * a1_0.w +
                (double)w1.x * a1_1.x + (double)w1.y * a1_1.y +
                (double)w1.z * a1_1.z + (double)w1.w * a1_1.w;
    double d2 = (double)w0.x * a2_0.x + (double)w0.y * a2_0.y +
                (double)w0.z * a2_0.z + (double)w0.w * a2_0.w +
                (double)w1.x * a2_1.x + (double)w1.y * a2_1.y +
                (double)w1.z * a2_1.z + (double)w1.w * a2_1.w;

    #pragma unroll
    for (int off = 32; off; off >>= 1) {
        d1 += __shfl_xor(d1, off);
        d2 += __shfl_xor(d2, off);
    }
    if (lane == 0) {
        v[k] = (float)d2;
        unsafeAtomicAdd(&scal[1], (double)h[k] * d1);
    }
}

// ---------------------------------------------------------------------------
// K2: one wave per 8 rows (4096 waves). Single pass over adj (128 MiB).
//   s_i = leaky_relu(c0 + dot(adj_i, v));  e_i = exp(s_i)  (no max-shift:
//   scores bounded, fp64 exp safe).  Z += e_i.  u[:] += e_i * adj_i  using the
//   row data still in registers.
// ---------------------------------------------------------------------------
__global__ __launch_bounds__(256) void k2_main(const float* __restrict__ adj,
                                               const float* __restrict__ v,
                                               double* __restrict__ scal,
                                               double* __restrict__ e,
                                               float* __restrict__ u) {
    const int wave = (blockIdx.x * blockDim.x + threadIdx.x) >> 6;  // 0..4095
    const int lane = threadIdx.x & 63;

    const double c0 = scal[1];

    // v fragment: this lane's 16 columns (4 segments x float4)
    const float4* v4 = (const float4*)v;
    float4 vf[4];
    #pragma unroll
    for (int q = 0; q < 4; ++q) vf[q] = v4[q * 64 + lane];

    float uacc[4][4] = {};
    double zacc = 0.0;

    const int row0 = wave * 8;
    for (int r = 0; r < 8; ++r) {
        const int row = row0 + r;
        const float4* arow = (const float4*)(adj + (size_t)row * FIN);
        float4 d[4];
        #pragma unroll
        for (int q = 0; q < 4; ++q) d[q] = arow[q * 64 + lane];

        double dot = 0.0;
        #pragma unroll
        for (int q = 0; q < 4; ++q) {
            dot += (double)d[q].x * vf[q].x + (double)d[q].y * vf[q].y +
                   (double)d[q].z * vf[q].z + (double)d[q].w * vf[q].w;
        }
        #pragma unroll
        for (int off = 32; off; off >>= 1) dot += __shfl_xor(dot, off);

        double s = c0 + dot;
        if (s < 0.0) s *= 0.1;        // leaky_relu, negative_slope=0.1
        const double ev = exp(s);
        zacc += ev;
        if (lane == 0) e[row] = ev;

        const float evf = (float)ev;
        #pragma unroll
        for (int q = 0; q < 4; ++q) {
            uacc[q][0] += evf * d[q].x;
            uacc[q][1] += evf * d[q].y;
            uacc[q][2] += evf * d[q].z;
            uacc[q][3] += evf * d[q].w;
        }
    }

    #pragma unroll
    for (int q = 0; q < 4; ++q) {
        const int col = q * 256 + 4 * lane;
        unsafeAtomicAdd(&u[col + 0], uacc[q][0]);
        unsafeAtomicAdd(&u[col + 1], uacc[q][1]);
        unsafeAtomicAdd(&u[col + 2], uacc[q][2]);
        unsafeAtomicAdd(&u[col + 3], uacc[q][3]);
    }
    if (lane == 0) unsafeAtomicAdd(&scal[0], zacc);
}

// ---------------------------------------------------------------------------
// K3: blocks 0..15  -> out[c] = (1/Z) * sum_k u[k] * W1[k][c]   (k split 16x64)
//     blocks 16..143-> attention2[i] = (N * e_i > Z) ? 1 : 0   (stored as f32)
// ---------------------------------------------------------------------------
__global__ __launch_bounds__(256) void k3_final(const double* __restrict__ e,
                                                const double* __restrict__ scal,
                                                const float* __restrict__ u,
                                                const float* __restrict__ W1,
                                                float* __restrict__ out) {
    const double Z = scal[0];
    if (blockIdx.x < 16) {
        const int b = blockIdx.x;
        const int t = threadIdx.x;  // 0..255 -> cols t and t+256
        float acc0 = 0.f, acc1 = 0.f;
        #pragma unroll 4
        for (int kk = 0; kk < 64; ++kk) {
            const int k = b * 64 + kk;
            const float uk = u[k];
            acc0 += uk * W1[(size_t)k * FOUT + t];
            acc1 += uk * W1[(size_t)k * FOUT + t + 256];
        }
        const float invZ = (float)(1.0 / Z);
        unsafeAtomicAdd(&out[t], acc0 * invZ);
        unsafeAtomicAdd(&out[t + 256], acc1 * invZ);
    } else {
        const int i = (blockIdx.x - 16) * 256 + threadIdx.x;  // 0..32767
        out[FOUT + i] = (e[i] * (double)NROWS > Z) ? 1.0f : 0.0f;
    }
}

extern "C" void kernel_launch(void* const* d_in, const int* in_sizes, int n_in,
                              void* d_out, int out_size, void* d_ws, size_t ws_size,
                              hipStream_t stream) {
    const float* h   = (const float*)d_in[0];   // (1, 1024)
    const float* adj = (const float*)d_in[1];   // (32768, 1024)
    const float* W   = (const float*)d_in[2];   // (1024, 512)
    const float* a   = (const float*)d_in[3];   // (1024, 1)
    const float* W1  = (const float*)d_in[4];   // (1024, 512)
    float* out = (float*)d_out;                 // [512 out fp32 | 32768 att2 as 0/1]

    double* e    = (double*)d_ws;               // [32768]
    double* scal = e + NROWS;                   // [8]: Z, c0
    float*  v    = (float*)(scal + 8);          // [1024]
    float*  u    = v + FIN;                     // [1024]

    hipMemsetAsync(d_ws, 0, WS_USED_BYTES, stream);
    hipMemsetAsync(d_out, 0, FOUT * sizeof(float), stream);

    k1_prep<<<dim3(256), dim3(256), 0, stream>>>(W, a, h, v, scal);
    k2_main<<<dim3(1024), dim3(256), 0, stream>>>(adj, v, scal, e, u);
    k3_final<<<dim3(144), dim3(256), 0, stream>>>(e, scal, u, W1, out);
}

// Round 4
// 230.632 us; speedup vs baseline: 2.5637x; 2.5637x over previous
//
#include <hip/hip_runtime.h>

static constexpr int NROWS = 32768;
static constexpr int FIN   = 1024;
static constexpr int FOUT  = 512;
static constexpr int NREP  = 16;     // u accumulator replicas (in d_out scratch)

// ws layout (total ~276 KB):
//   double e[32768]     : unnormalized exp(scores)        (256 KB)
//   double hpart[1024]  : h[k] * (W@a1)[k]                (8 KB)
//   double zpart[1024]  : per-K2-block partial of Z       (8 KB)
//   float  v[1024]      : W @ a2                          (4 KB)
//
// d_out layout: [0:512) out fp32 | [512:33280) attention2 as 0.0/1.0
//   The 64 KB at out[512 : 512+16384) is borrowed as u16[16][1024] replica
//   accumulators between K2 and K3a; K3b overwrites it with attention2.

// ---------------------------------------------------------------------------
// K1: one wave per k (1024 waves). No atomics.
//   v[k]     = sum_j W[k][j] * a2[j]
//   hpart[k] = h[k] * sum_j W[k][j] * a1[j]
// ---------------------------------------------------------------------------
__global__ __launch_bounds__(256) void k1_prep(const float* __restrict__ W,
                                               const float* __restrict__ a,
                                               const float* __restrict__ h,
                                               float* __restrict__ v,
                                               double* __restrict__ hpart) {
    const int k    = (blockIdx.x * blockDim.x + threadIdx.x) >> 6;  // 0..1023
    const int lane = threadIdx.x & 63;

    const float4* Wrow = (const float4*)(W + (size_t)k * FOUT);
    float4 w0 = Wrow[lane];
    float4 w1 = Wrow[64 + lane];

    const float4* a4 = (const float4*)a;
    float4 a1_0 = a4[lane];
    float4 a1_1 = a4[64 + lane];
    float4 a2_0 = a4[128 + lane];
    float4 a2_1 = a4[192 + lane];

    double d1 = (double)w0.x * a1_0.x + (double)w0.y * a1_0.y +
                (double)w0.z * a1_0.z + (double)w0.w * a1_0.w +
                (double)w1.x * a1_1.x + (double)w1.y * a1_1.y +
                (double)w1.z * a1_1.z + (double)w1.w * a1_1.w;
    double d2 = (double)w0.x * a2_0.x + (double)w0.y * a2_0.y +
                (double)w0.z * a2_0.z + (double)w0.w * a2_0.w +
                (double)w1.x * a2_1.x + (double)w1.y * a2_1.y +
                (double)w1.z * a2_1.z + (double)w1.w * a2_1.w;

    #pragma unroll
    for (int off = 32; off; off >>= 1) {
        d1 += __shfl_xor(d1, off);
        d2 += __shfl_xor(d2, off);
    }
    if (lane == 0) {
        v[k]     = (float)d2;
        hpart[k] = (double)h[k] * d1;
    }
}

// ---------------------------------------------------------------------------
// K2: 1024 blocks x 256 threads (4096 waves, 8 rows/wave). Single adj pass.
// Per-block LDS reduce of u, then 4 fp32 atomics/thread into replica
// u16[blockIdx&15][:] -> same-address chain length 64 only.
// c0 reduced redundantly per wave from hpart (deterministic order).
// NOTE: after the dot butterfly, ev/zacc are wave-uniform — do NOT butterfly
// zacc again (that was the x64 Z bug in rounds 2-3).
// ---------------------------------------------------------------------------
__global__ __launch_bounds__(256) void k2_main(const float* __restrict__ adj,
                                               const float* __restrict__ v,
                                               const double* __restrict__ hpart,
                                               double* __restrict__ e,
                                               float* __restrict__ u16,   // [16][1024]
                                               double* __restrict__ zpart) {
    __shared__ float  uls[4][1024];
    __shared__ double zls[4];

    const int wave  = threadIdx.x >> 6;               // 0..3
    const int lane  = threadIdx.x & 63;
    const int gwave = blockIdx.x * 4 + wave;          // 0..4095

    // c0 = sum(hpart), identical order in every wave -> bitwise-identical
    double c0 = 0.0;
    #pragma unroll
    for (int j = 0; j < 16; ++j) c0 += hpart[j * 64 + lane];
    #pragma unroll
    for (int off = 32; off; off >>= 1) c0 += __shfl_xor(c0, off);

    const float4* v4 = (const float4*)v;
    float4 vf[4];
    #pragma unroll
    for (int q = 0; q < 4; ++q) vf[q] = v4[q * 64 + lane];

    float  uacc[4][4] = {};
    double zacc = 0.0;   // wave-uniform (ev is uniform after dot butterfly)

    const int row0 = gwave * 8;
    for (int r = 0; r < 8; ++r) {
        const int row = row0 + r;
        const float4* arow = (const float4*)(adj + (size_t)row * FIN);
        float4 d[4];
        #pragma unroll
        for (int q = 0; q < 4; ++q) d[q] = arow[q * 64 + lane];

        double dot = 0.0;
        #pragma unroll
        for (int q = 0; q < 4; ++q) {
            dot += (double)d[q].x * vf[q].x + (double)d[q].y * vf[q].y +
                   (double)d[q].z * vf[q].z + (double)d[q].w * vf[q].w;
        }
        #pragma unroll
        for (int off = 32; off; off >>= 1) dot += __shfl_xor(dot, off);

        double s = c0 + dot;
        if (s < 0.0) s *= 0.1;       // leaky_relu(0.1)
        const double ev = exp(s);    // wave-uniform
        zacc += ev;
        if (lane == 0) e[row] = ev;

        const float evf = (float)ev;
        #pragma unroll
        for (int q = 0; q < 4; ++q) {
            uacc[q][0] += evf * d[q].x;
            uacc[q][1] += evf * d[q].y;
            uacc[q][2] += evf * d[q].z;
            uacc[q][3] += evf * d[q].w;
        }
    }

    // per-wave u partial -> LDS (conflict-free b128 writes)
    float4* uls4w = (float4*)&uls[wave][0];
    #pragma unroll
    for (int q = 0; q < 4; ++q)
        uls4w[q * 64 + lane] = make_float4(uacc[q][0], uacc[q][1], uacc[q][2], uacc[q][3]);

    // zacc already holds this wave's full sum in every lane — just publish it.
    if (lane == 0) zls[wave] = zacc;

    __syncthreads();

    // cross-wave reduce; thread t owns cols 4t..4t+3
    const int t = threadIdx.x;
    const float4* uls4 = (const float4*)uls;
    float4 s0 = uls4[t];
    float4 s1 = uls4[256 + t];
    float4 s2 = uls4[512 + t];
    float4 s3 = uls4[768 + t];

    float* urep = u16 + (size_t)(blockIdx.x & (NREP - 1)) * 1024 + 4 * t;
    unsafeAtomicAdd(&urep[0], s0.x + s1.x + s2.x + s3.x);
    unsafeAtomicAdd(&urep[1], s0.y + s1.y + s2.y + s3.y);
    unsafeAtomicAdd(&urep[2], s0.z + s1.z + s2.z + s3.z);
    unsafeAtomicAdd(&urep[3], s0.w + s1.w + s2.w + s3.w);

    if (t == 0) zpart[blockIdx.x] = zls[0] + zls[1] + zls[2] + zls[3];
}

// ---------------------------------------------------------------------------
// Deterministic Z from zpart (identical order in every block).
// ---------------------------------------------------------------------------
__device__ __forceinline__ double block_reduce_Z(const double* __restrict__ zpart,
                                                 double* zs) {
    const int t = threadIdx.x;
    zs[t] = zpart[t] + zpart[256 + t] + zpart[512 + t] + zpart[768 + t];
    __syncthreads();
    for (int st = 128; st > 0; st >>= 1) {
        if (t < st) zs[t] += zs[t + st];
        __syncthreads();
    }
    double Z = zs[0];
    __syncthreads();
    return Z;
}

// ---------------------------------------------------------------------------
// K3a: 16 blocks. out[0:512] = (u/Z) @ W1. Reads u16 replicas (in d_out),
// so MUST run before K3b overwrites that region.
// ---------------------------------------------------------------------------
__global__ __launch_bounds__(256) void k3a_out(const double* __restrict__ zpart,
                                               const float* __restrict__ u16,
                                               const float* __restrict__ W1,
                                               float* __restrict__ out) {
    __shared__ double zs[256];
    __shared__ float  us[1024];
    __shared__ float  red[8][32];
    const double Z = block_reduce_Z(zpart, zs);
    const int t = threadIdx.x;

    // us[k] = sum over 16 replicas
    #pragma unroll
    for (int g = 0; g < 4; ++g) {
        const int k = g * 256 + t;
        float s = 0.f;
        #pragma unroll
        for (int rep = 0; rep < NREP; ++rep) s += u16[rep * 1024 + k];
        us[k] = s;
    }
    __syncthreads();

    const int cl  = t & 31;               // col within block's 32-col slab
    const int kg  = t >> 5;               // 0..7 k-group
    const int col = blockIdx.x * 32 + cl;
    float acc = 0.f;
    #pragma unroll 4
    for (int kk = 0; kk < 128; ++kk) {
        const int k = kg * 128 + kk;
        acc += us[k] * W1[(size_t)k * FOUT + col];
    }
    red[kg][cl] = acc;
    __syncthreads();
    if (t < 32) {
        float tot = 0.f;
        #pragma unroll
        for (int g = 0; g < 8; ++g) tot += red[g][t];
        out[blockIdx.x * 32 + t] = (float)((double)tot / Z);
    }
}

// ---------------------------------------------------------------------------
// K3b: 128 blocks. attention2[i] = (N*e_i > Z) ? 1 : 0 (as f32 0/1).
// Overwrites the u16 scratch region — runs after K3a.
// ---------------------------------------------------------------------------
__global__ __launch_bounds__(256) void k3b_att2(const double* __restrict__ e,
                                                const double* __restrict__ zpart,
                                                float* __restrict__ out) {
    __shared__ double zs[256];
    const double Z = block_reduce_Z(zpart, zs);
    const int i = blockIdx.x * 256 + threadIdx.x;   // 0..32767
    out[FOUT + i] = (e[i] * (double)NROWS > Z) ? 1.0f : 0.0f;
}

extern "C" void kernel_launch(void* const* d_in, const int* in_sizes, int n_in,
                              void* d_out, int out_size, void* d_ws, size_t ws_size,
                              hipStream_t stream) {
    const float* h   = (const float*)d_in[0];   // (1, 1024)
    const float* adj = (const float*)d_in[1];   // (32768, 1024)
    const float* W   = (const float*)d_in[2];   // (1024, 512)
    const float* a   = (const float*)d_in[3];   // (1024, 1)
    const float* W1  = (const float*)d_in[4];   // (1024, 512)
    float* out = (float*)d_out;

    double* e     = (double*)d_ws;              // [32768]
    double* hpart = e + NROWS;                  // [1024]
    double* zpart = hpart + 1024;               // [1024]
    float*  v     = (float*)(zpart + 1024);     // [1024]

    float* u16 = out + FOUT;                    // [16][1024] scratch in d_out

    hipMemsetAsync(u16, 0, NREP * 1024 * sizeof(float), stream);

    k1_prep<<<dim3(256), dim3(256), 0, stream>>>(W, a, h, v, hpart);
    k2_main<<<dim3(1024), dim3(256), 0, stream>>>(adj, v, hpart, e, u16, zpart);
    k3a_out<<<dim3(16),  dim3(256), 0, stream>>>(zpart, u16, W1, out);
    k3b_att2<<<dim3(128), dim3(256), 0, stream>>>(e, zpart, out);
}

// Round 5
// 225.372 us; speedup vs baseline: 2.6235x; 1.0233x over previous
//
#include <hip/hip_runtime.h>

static constexpr int NROWS = 32768;
static constexpr int FIN   = 1024;
static constexpr int FOUT  = 512;
static constexpr int NREP  = 16;     // u accumulator replicas

// ws layout (total ~340 KB of the 512 MiB available):
//   double e[32768]       : unnormalized exp(scores)        (256 KB)
//   double hpart[1024]    : h[k] * (W@a1)[k]                (8 KB)
//   double zpart[1024]    : per-K2-block partial of Z       (8 KB)
//   float  v[1024]        : W @ a2                          (4 KB)
//   float  u16[16][1024]  : replicated u accumulators       (64 KB)
//
// d_out layout: [0:512) out fp32 | [512:33280) attention2 as 0.0/1.0

// ---------------------------------------------------------------------------
// K1: one wave per k (1024 waves). No atomics. Blocks 0..15 also zero u16.
//   v[k]     = sum_j W[k][j] * a2[j]
//   hpart[k] = h[k] * sum_j W[k][j] * a1[j]
// ---------------------------------------------------------------------------
__global__ __launch_bounds__(256) void k1_prep(const float* __restrict__ W,
                                               const float* __restrict__ a,
                                               const float* __restrict__ h,
                                               float* __restrict__ v,
                                               double* __restrict__ hpart,
                                               float* __restrict__ u16) {
    if (blockIdx.x < 16) {
        // zero u16[16][1024]: 16 blocks x 256 threads x 1 float4
        ((float4*)u16)[blockIdx.x * 256 + threadIdx.x] =
            make_float4(0.f, 0.f, 0.f, 0.f);
    }

    const int k    = (blockIdx.x * blockDim.x + threadIdx.x) >> 6;  // 0..1023
    const int lane = threadIdx.x & 63;

    const float4* Wrow = (const float4*)(W + (size_t)k * FOUT);
    float4 w0 = Wrow[lane];
    float4 w1 = Wrow[64 + lane];

    const float4* a4 = (const float4*)a;
    float4 a1_0 = a4[lane];
    float4 a1_1 = a4[64 + lane];
    float4 a2_0 = a4[128 + lane];
    float4 a2_1 = a4[192 + lane];

    double d1 = (double)w0.x * a1_0.x + (double)w0.y * a1_0.y +
                (double)w0.z * a1_0.z + (double)w0.w * a1_0.w +
                (double)w1.x * a1_1.x + (double)w1.y * a1_1.y +
                (double)w1.z * a1_1.z + (double)w1.w * a1_1.w;
    double d2 = (double)w0.x * a2_0.x + (double)w0.y * a2_0.y +
                (double)w0.z * a2_0.z + (double)w0.w * a2_0.w +
                (double)w1.x * a2_1.x + (double)w1.y * a2_1.y +
                (double)w1.z * a2_1.z + (double)w1.w * a2_1.w;

    #pragma unroll
    for (int off = 32; off; off >>= 1) {
        d1 += __shfl_xor(d1, off);
        d2 += __shfl_xor(d2, off);
    }
    if (lane == 0) {
        v[k]     = (float)d2;
        hpart[k] = (double)h[k] * d1;
    }
}

// ---------------------------------------------------------------------------
// K2: 1024 blocks x 256 threads (4096 waves, 8 rows/wave). Single adj pass.
// Per-block LDS reduce of u, then 4 fp32 atomics/thread into replica
// u16[blockIdx&15][:] -> same-address chain length 64.
// c0 reduced redundantly per wave from hpart (deterministic order).
// NOTE: after the dot butterfly, ev/zacc are wave-uniform — no zacc butterfly
// (the x64 Z bug of rounds 2-3).
// ---------------------------------------------------------------------------
__global__ __launch_bounds__(256) void k2_main(const float* __restrict__ adj,
                                               const float* __restrict__ v,
                                               const double* __restrict__ hpart,
                                               double* __restrict__ e,
                                               float* __restrict__ u16,   // [16][1024]
                                               double* __restrict__ zpart) {
    __shared__ float  uls[4][1024];
    __shared__ double zls[4];

    const int wave  = threadIdx.x >> 6;               // 0..3
    const int lane  = threadIdx.x & 63;
    const int gwave = blockIdx.x * 4 + wave;          // 0..4095

    // c0 = sum(hpart), identical order in every wave -> bitwise-identical
    double c0 = 0.0;
    #pragma unroll
    for (int j = 0; j < 16; ++j) c0 += hpart[j * 64 + lane];
    #pragma unroll
    for (int off = 32; off; off >>= 1) c0 += __shfl_xor(c0, off);

    const float4* v4 = (const float4*)v;
    float4 vf[4];
    #pragma unroll
    for (int q = 0; q < 4; ++q) vf[q] = v4[q * 64 + lane];

    float  uacc[4][4] = {};
    double zacc = 0.0;   // wave-uniform

    const int row0 = gwave * 8;
    for (int r = 0; r < 8; ++r) {
        const int row = row0 + r;
        const float4* arow = (const float4*)(adj + (size_t)row * FIN);
        float4 d[4];
        #pragma unroll
        for (int q = 0; q < 4; ++q) d[q] = arow[q * 64 + lane];

        double dot = 0.0;
        #pragma unroll
        for (int q = 0; q < 4; ++q) {
            dot += (double)d[q].x * vf[q].x + (double)d[q].y * vf[q].y +
                   (double)d[q].z * vf[q].z + (double)d[q].w * vf[q].w;
        }
        #pragma unroll
        for (int off = 32; off; off >>= 1) dot += __shfl_xor(dot, off);

        double s = c0 + dot;
        if (s < 0.0) s *= 0.1;       // leaky_relu(0.1)
        const double ev = exp(s);    // wave-uniform
        zacc += ev;
        if (lane == 0) e[row] = ev;

        const float evf = (float)ev;
        #pragma unroll
        for (int q = 0; q < 4; ++q) {
            uacc[q][0] += evf * d[q].x;
            uacc[q][1] += evf * d[q].y;
            uacc[q][2] += evf * d[q].z;
            uacc[q][3] += evf * d[q].w;
        }
    }

    // per-wave u partial -> LDS (conflict-free b128 writes)
    float4* uls4w = (float4*)&uls[wave][0];
    #pragma unroll
    for (int q = 0; q < 4; ++q)
        uls4w[q * 64 + lane] = make_float4(uacc[q][0], uacc[q][1], uacc[q][2], uacc[q][3]);

    if (lane == 0) zls[wave] = zacc;   // zacc already wave-complete

    __syncthreads();

    // cross-wave reduce; thread t owns cols 4t..4t+3
    const int t = threadIdx.x;
    const float4* uls4 = (const float4*)uls;
    float4 s0 = uls4[t];
    float4 s1 = uls4[256 + t];
    float4 s2 = uls4[512 + t];
    float4 s3 = uls4[768 + t];

    float* urep = u16 + (size_t)(blockIdx.x & (NREP - 1)) * 1024 + 4 * t;
    unsafeAtomicAdd(&urep[0], s0.x + s1.x + s2.x + s3.x);
    unsafeAtomicAdd(&urep[1], s0.y + s1.y + s2.y + s3.y);
    unsafeAtomicAdd(&urep[2], s0.z + s1.z + s2.z + s3.z);
    unsafeAtomicAdd(&urep[3], s0.w + s1.w + s2.w + s3.w);

    if (t == 0) zpart[blockIdx.x] = zls[0] + zls[1] + zls[2] + zls[3];
}

// ---------------------------------------------------------------------------
// Deterministic Z from zpart (identical order in every block).
// ---------------------------------------------------------------------------
__device__ __forceinline__ double block_reduce_Z(const double* __restrict__ zpart,
                                                 double* zs) {
    const int t = threadIdx.x;
    zs[t] = zpart[t] + zpart[256 + t] + zpart[512 + t] + zpart[768 + t];
    __syncthreads();
    for (int st = 128; st > 0; st >>= 1) {
        if (t < st) zs[t] += zs[t + st];
        __syncthreads();
    }
    double Z = zs[0];
    __syncthreads();
    return Z;
}

// ---------------------------------------------------------------------------
// K3 (fused): blocks 0..15   -> out[0:512] = (u/Z) @ W1   (u16 lives in ws,
//                               no aliasing with d_out -> safe to fuse)
//             blocks 16..143 -> out[512+i] = (N*e_i > Z) ? 1 : 0
// ---------------------------------------------------------------------------
__global__ __launch_bounds__(256) void k3_final(const double* __restrict__ e,
                                                const double* __restrict__ zpart,
                                                const float* __restrict__ u16,
                                                const float* __restrict__ W1,
                                                float* __restrict__ out) {
    __shared__ double zs[256];
    const double Z = block_reduce_Z(zpart, zs);
    const int t = threadIdx.x;

    if (blockIdx.x < 16) {
        __shared__ float us[1024];
        __shared__ float red[8][32];

        // us[k] = sum over 16 replicas
        #pragma unroll
        for (int g = 0; g < 4; ++g) {
            const int k = g * 256 + t;
            float s = 0.f;
            #pragma unroll
            for (int rep = 0; rep < NREP; ++rep) s += u16[rep * 1024 + k];
            us[k] = s;
        }
        __syncthreads();

        const int cl  = t & 31;               // col within 32-col slab
        const int kg  = t >> 5;               // 0..7 k-group
        const int col = blockIdx.x * 32 + cl;
        float acc = 0.f;
        #pragma unroll 4
        for (int kk = 0; kk < 128; ++kk) {
            const int k = kg * 128 + kk;
            acc += us[k] * W1[(size_t)k * FOUT + col];
        }
        red[kg][cl] = acc;
        __syncthreads();
        if (t < 32) {
            float tot = 0.f;
            #pragma unroll
            for (int g = 0; g < 8; ++g) tot += red[g][t];
            out[blockIdx.x * 32 + t] = (float)((double)tot / Z);
        }
    } else {
        const int i = (blockIdx.x - 16) * 256 + t;   // 0..32767
        out[FOUT + i] = (e[i] * (double)NROWS > Z) ? 1.0f : 0.0f;
    }
}

extern "C" void kernel_launch(void* const* d_in, const int* in_sizes, int n_in,
                              void* d_out, int out_size, void* d_ws, size_t ws_size,
                              hipStream_t stream) {
    const float* h   = (const float*)d_in[0];   // (1, 1024)
    const float* adj = (const float*)d_in[1];   // (32768, 1024)
    const float* W   = (const float*)d_in[2];   // (1024, 512)
    const float* a   = (const float*)d_in[3];   // (1024, 1)
    const float* W1  = (const float*)d_in[4];   // (1024, 512)
    float* out = (float*)d_out;

    double* e     = (double*)d_ws;              // [32768]
    double* hpart = e + NROWS;                  // [1024]
    double* zpart = hpart + 1024;               // [1024]
    float*  v     = (float*)(zpart + 1024);     // [1024]
    float*  u16   = v + 1024;                   // [16][1024]

    k1_prep<<<dim3(256),  dim3(256), 0, stream>>>(W, a, h, v, hpart, u16);
    k2_main<<<dim3(1024), dim3(256), 0, stream>>>(adj, v, hpart, e, u16, zpart);
    k3_final<<<dim3(144), dim3(256), 0, stream>>>(e, zpart, u16, W1, out);
}